// Round 5
// baseline (631.116 us; speedup 1.0000x reference)
//
#include <hip/hip_runtime.h>
#include <math.h>

#define NB    4
#define PP    1024
#define DD    32
#define MAXIT 30
#define MBLK  512     // main-kernel grid: 8 rows/block, 128 blocks/batch
#define BTHR  256

// All state in module-scope device globals; rewritten every call.
__device__ float  g_C[NB*PP*PP];     // C[n][p][q], 16 MB
__device__ float  g_logmu[NB*PP], g_lognu[NB*PP];
__device__ float  g_u[NB*PP], g_v[NB*PP];
__device__ float2 g_pms[MBLK*PP];    // column partials (m,s): [n][bb][q], 4 MB
__device__ double g_errpart[MAXIT*MBLK];
__device__ int    g_done[MAXIT+1];
__device__ double g_costpart[1024];

// ---------------------------------------------------------------------------
__global__ __launch_bounds__(BTHR)
void prep_kernel(const float* __restrict__ xw, const float* __restrict__ yw)
{
    const int t = threadIdx.x, lane = t & 63, wid = t >> 6;
    double sx = 0.0, sy = 0.0;
    for (int i = t; i < NB*PP; i += BTHR) { sx += (double)xw[i]; sy += (double)yw[i]; }
#pragma unroll
    for (int o = 32; o > 0; o >>= 1) { sx += __shfl_xor(sx, o); sy += __shfl_xor(sy, o); }
    __shared__ double a[4], b[4];
    if (lane == 0) { a[wid] = sx; b[wid] = sy; }
    __syncthreads();
    const double Sx = ((a[0]+a[1])+a[2])+a[3];
    const double Sy = ((b[0]+b[1])+b[2])+b[3];
    for (int i = t; i < NB*PP; i += BTHR) {
        g_logmu[i] = (float)log((double)xw[i]/Sx + 1e-8);
        g_lognu[i] = (float)log((double)yw[i]/Sy + 1e-8);
        g_u[i] = 0.f;
        g_v[i] = 0.f;
    }
    if (t <= MAXIT) g_done[t] = 0;
}

// ---------------------------------------------------------------------------
// Build C only (no Ct needed anymore). Block owns 8 rows; thread t owns cols
// {t, t+256, t+512, t+768} with register accumulators (no scratch).
__global__ __launch_bounds__(BTHR)
void build_kernel(const float* __restrict__ x, const float* __restrict__ y)
{
    const int t = threadIdx.x;
    const int b = blockIdx.x;                // 0..511
    const int n = b >> 7;
    const int nbase = n << 10;
    const int gr0 = b << 3;

    __shared__ float rows[8][DD];
    {
        const int r = t >> 5, d = t & 31;
        rows[r][d] = x[(gr0 + r) * DD + d];
    }
    __syncthreads();

    const float4* op0 = reinterpret_cast<const float4*>(y + ((size_t)(nbase + t      ) << 5));
    const float4* op1 = reinterpret_cast<const float4*>(y + ((size_t)(nbase + t + 256) << 5));
    const float4* op2 = reinterpret_cast<const float4*>(y + ((size_t)(nbase + t + 512) << 5));
    const float4* op3 = reinterpret_cast<const float4*>(y + ((size_t)(nbase + t + 768) << 5));

    float acc0[8], acc1[8], acc2[8], acc3[8];
#pragma unroll
    for (int r = 0; r < 8; ++r) { acc0[r]=0.f; acc1[r]=0.f; acc2[r]=0.f; acc3[r]=0.f; }

#pragma unroll
    for (int j = 0; j < 8; ++j) {
        const float4 f0 = op0[j], f1 = op1[j], f2 = op2[j], f3 = op3[j];
#pragma unroll
        for (int r = 0; r < 8; ++r) {
            const float4 rv = *reinterpret_cast<const float4*>(&rows[r][4*j]);
            float d;
            d = rv.x-f0.x; acc0[r]=fmaf(d,d,acc0[r]);
            d = rv.y-f0.y; acc0[r]=fmaf(d,d,acc0[r]);
            d = rv.z-f0.z; acc0[r]=fmaf(d,d,acc0[r]);
            d = rv.w-f0.w; acc0[r]=fmaf(d,d,acc0[r]);
            d = rv.x-f1.x; acc1[r]=fmaf(d,d,acc1[r]);
            d = rv.y-f1.y; acc1[r]=fmaf(d,d,acc1[r]);
            d = rv.z-f1.z; acc1[r]=fmaf(d,d,acc1[r]);
            d = rv.w-f1.w; acc1[r]=fmaf(d,d,acc1[r]);
            d = rv.x-f2.x; acc2[r]=fmaf(d,d,acc2[r]);
            d = rv.y-f2.y; acc2[r]=fmaf(d,d,acc2[r]);
            d = rv.z-f2.z; acc2[r]=fmaf(d,d,acc2[r]);
            d = rv.w-f2.w; acc2[r]=fmaf(d,d,acc2[r]);
            d = rv.x-f3.x; acc3[r]=fmaf(d,d,acc3[r]);
            d = rv.y-f3.y; acc3[r]=fmaf(d,d,acc3[r]);
            d = rv.z-f3.z; acc3[r]=fmaf(d,d,acc3[r]);
            d = rv.w-f3.w; acc3[r]=fmaf(d,d,acc3[r]);
        }
    }
#pragma unroll
    for (int r = 0; r < 8; ++r) {
        float* row = g_C + (((size_t)(gr0 + r)) << 10);
        row[t      ] = acc0[r];
        row[t + 256] = acc1[r];
        row[t + 512] = acc2[r];
        row[t + 768] = acc3[r];
    }
}

// ---------------------------------------------------------------------------
// Fused phase: u-update for the block's 8 rows + per-column online-softmax
// partials over those rows (feeds the v-update). C is read ONCE.
__global__ __launch_bounds__(BTHR)
void main_kernel(int it)
{
    const int t = threadIdx.x, lane = t & 63, wid = t >> 6;
    const int b = blockIdx.x;
    const int n = b >> 7;
    const int nbase = n << 10;
    const int done = g_done[it];
    const int gr0 = (b << 3) + (wid << 1);   // wave's 2 rows

    __shared__ float2 lpm[4][PP];            // 32 KB: per-wave column partials
    __shared__ double dred[4];

    // v for this lane's 16 columns
    const float4* Vp = reinterpret_cast<const float4*>(g_v + nbase);
    float vv[16];
    {
#pragma unroll
        for (int k = 0; k < 4; ++k) {
            const float4 f = Vp[lane + (k << 6)];
            vv[4*k+0]=f.x; vv[4*k+1]=f.y; vv[4*k+2]=f.z; vv[4*k+3]=f.w;
        }
    }
    // the 2 C rows
    float c0[16], c1[16];
    {
        const float4* C0 = reinterpret_cast<const float4*>(g_C + ((size_t)gr0 << 10));
        const float4* C1 = reinterpret_cast<const float4*>(g_C + ((size_t)(gr0+1) << 10));
#pragma unroll
        for (int k = 0; k < 4; ++k) {
            float4 f = C0[lane + (k << 6)];
            c0[4*k+0]=f.x; c0[4*k+1]=f.y; c0[4*k+2]=f.z; c0[4*k+3]=f.w;
            f = C1[lane + (k << 6)];
            c1[4*k+0]=f.x; c1[4*k+1]=f.y; c1[4*k+2]=f.z; c1[4*k+3]=f.w;
        }
    }

    // ---- u-update (log-domain lse across the 64-lane row) ----
    float tv0[16], tv1[16];
    float mx0 = -1e30f, mx1 = -1e30f;
#pragma unroll
    for (int i = 0; i < 16; ++i) {
        tv0[i] = (vv[i] - c0[i]) * 10.f;  mx0 = fmaxf(mx0, tv0[i]);
        tv1[i] = (vv[i] - c1[i]) * 10.f;  mx1 = fmaxf(mx1, tv1[i]);
    }
#pragma unroll
    for (int o = 32; o > 0; o >>= 1) {
        mx0 = fmaxf(mx0, __shfl_xor(mx0, o));
        mx1 = fmaxf(mx1, __shfl_xor(mx1, o));
    }
    float s0 = 0.f, s1 = 0.f;
#pragma unroll
    for (int i = 0; i < 16; ++i) {
        s0 += __expf(tv0[i] - mx0);
        s1 += __expf(tv1[i] - mx1);
    }
#pragma unroll
    for (int o = 32; o > 0; o >>= 1) {
        s0 += __shfl_xor(s0, o);
        s1 += __shfl_xor(s1, o);
    }
    const float un0 = 0.1f * (g_logmu[gr0]   - (mx0 + __logf(s0)));
    const float un1 = 0.1f * (g_logmu[gr0+1] - (mx1 + __logf(s1)));
    const float uo0 = g_u[gr0], uo1 = g_u[gr0+1];
    const float uc0 = done ? uo0 : un0;      // committed u (freeze semantics)
    const float uc1 = done ? uo1 : un1;
    if (lane == 0) {
        if (!done) { g_u[gr0] = un0; g_u[gr0+1] = un1; }
        dred[wid] = fabs((double)un0 - (double)uo0) + fabs((double)un1 - (double)uo1);
    }

    // ---- column partials over this wave's 2 rows ----
#pragma unroll
    for (int k = 0; k < 4; ++k) {
#pragma unroll
        for (int j = 0; j < 4; ++j) {
            const int i = 4*k + j;
            const float a0 = (uc0 - c0[i]) * 10.f;
            const float a1 = (uc1 - c1[i]) * 10.f;
            const float m  = fmaxf(a0, a1);
            const float s  = __expf(a0 - m) + __expf(a1 - m);
            lpm[wid][4*(lane + (k << 6)) + j] = make_float2(m, s);
        }
    }
    __syncthreads();

    // block-level 4-way merge + global partial write + err partial
    if (t == 0) g_errpart[(size_t)it * MBLK + b] = ((dred[0]+dred[1])+dred[2])+dred[3];
#pragma unroll
    for (int c = 0; c < 4; ++c) {
        const int q = t + (c << 8);
        const float2 a = lpm[0][q], b2 = lpm[1][q], c2 = lpm[2][q], d2 = lpm[3][q];
        const float M = fmaxf(fmaxf(a.x, b2.x), fmaxf(c2.x, d2.x));
        const float S = a.y*__expf(a.x-M) + b2.y*__expf(b2.x-M)
                      + c2.y*__expf(c2.x-M) + d2.y*__expf(d2.x-M);
        g_pms[((size_t)b << 10) + q] = make_float2(M, S);
    }
}

// ---------------------------------------------------------------------------
// Combine: v_new[q] from 128 block partials; block 0 also finalizes err/done.
__global__ __launch_bounds__(BTHR)
void combine_kernel(int it)
{
    const int t = threadIdx.x;
    const int g = (blockIdx.x << 8) + t;     // 16 blocks x 256 = 4096
    const int n = g >> 10, q = g & 1023;
    const int done = g_done[it];

    if (blockIdx.x == 0) {                   // err total -> done flag for it+1
        const double* p = g_errpart + (size_t)it * MBLK;
        double s = p[t] + p[t + 256];
#pragma unroll
        for (int o = 32; o > 0; o >>= 1) s += __shfl_xor(s, o);
        __shared__ double sred[4];
        if ((t & 63) == 0) sred[t >> 6] = s;
        __syncthreads();
        if (t == 0) {
            const double tot = ((sred[0]+sred[1])+sred[2])+sred[3];
            g_done[it + 1] = done | (tot < 0.4);   // total<0.4 <=> mean<0.1
        }
    }

    const float2* P = g_pms + ((size_t)n << 17) + q;   // [n][bb][q]
    float M0=-1e30f,M1=-1e30f,M2=-1e30f,M3=-1e30f;
    float S0=0.f,S1=0.f,S2=0.f,S3=0.f;
#pragma unroll 4
    for (int bb = 0; bb < 128; bb += 4) {
        const float2 p0 = P[(size_t)(bb+0) << 10];
        const float2 p1 = P[(size_t)(bb+1) << 10];
        const float2 p2 = P[(size_t)(bb+2) << 10];
        const float2 p3 = P[(size_t)(bb+3) << 10];
        float nm;
        nm = fmaxf(M0, p0.x); S0 = S0*__expf(M0-nm) + p0.y*__expf(p0.x-nm); M0 = nm;
        nm = fmaxf(M1, p1.x); S1 = S1*__expf(M1-nm) + p1.y*__expf(p1.x-nm); M1 = nm;
        nm = fmaxf(M2, p2.x); S2 = S2*__expf(M2-nm) + p2.y*__expf(p2.x-nm); M2 = nm;
        nm = fmaxf(M3, p3.x); S3 = S3*__expf(M3-nm) + p3.y*__expf(p3.x-nm); M3 = nm;
    }
    const float M = fmaxf(fmaxf(M0, M1), fmaxf(M2, M3));
    const float S = S0*__expf(M0-M) + S1*__expf(M1-M) + S2*__expf(M2-M) + S3*__expf(M3-M);
    const float vnew = 0.1f * (g_lognu[g] - (M + __logf(S)));
    if (!done) g_v[g] = vnew;
}

// ---------------------------------------------------------------------------
// cost = sum_pq exp((u_p + v_q - C_pq)*10) * C_pq, per batch (f64 partials).
__global__ __launch_bounds__(BTHR)
void cost_kernel()
{
    const int t = threadIdx.x, lane = t & 63, wid = t >> 6;
    const int b = blockIdx.x;
    const int n = b >> 8;
    const int nbase = n << 10;
    const int gr = (b << 2) + wid;

    const float4* Vp = reinterpret_cast<const float4*>(g_v + nbase);
    const float4* Cp = reinterpret_cast<const float4*>(g_C + ((size_t)gr << 10));
    const float ur = g_u[gr];

    double part = 0.0;
#pragma unroll
    for (int k = 0; k < 4; ++k) {
        const float4 cf = Cp[lane + (k << 6)];
        const float4 vf = Vp[lane + (k << 6)];
        part += (double)__expf((ur + vf.x - cf.x) * 10.f) * (double)cf.x;
        part += (double)__expf((ur + vf.y - cf.y) * 10.f) * (double)cf.y;
        part += (double)__expf((ur + vf.z - cf.z) * 10.f) * (double)cf.z;
        part += (double)__expf((ur + vf.w - cf.w) * 10.f) * (double)cf.w;
    }
#pragma unroll
    for (int o = 32; o > 0; o >>= 1) part += __shfl_xor(part, o);
    __shared__ double red[4];
    if (lane == 0) red[wid] = part;
    __syncthreads();
    if (t == 0) g_costpart[b] = ((red[0]+red[1])+red[2])+red[3];
}

__global__ __launch_bounds__(64)
void out_kernel(float* __restrict__ out)
{
    const int t = threadIdx.x;   // 64 threads
#pragma unroll 1
    for (int n = 0; n < NB; ++n) {
        const double* cp = g_costpart + (n << 8);
        double s = ((cp[t] + cp[t+64]) + cp[t+128]) + cp[t+192];
#pragma unroll
        for (int o = 32; o > 0; o >>= 1) s += __shfl_xor(s, o);
        if (t == 0) out[n] = (float)s;
    }
}

// ---------------------------------------------------------------------------
extern "C" void kernel_launch(void* const* d_in, const int* in_sizes, int n_in,
                              void* d_out, int out_size, void* d_ws, size_t ws_size,
                              hipStream_t stream)
{
    (void)in_sizes; (void)n_in; (void)out_size; (void)d_ws; (void)ws_size;
    const float* x  = (const float*)d_in[0];
    const float* y  = (const float*)d_in[1];
    const float* xw = (const float*)d_in[2];
    const float* yw = (const float*)d_in[3];
    float* out = (float*)d_out;

    hipLaunchKernelGGL(prep_kernel,  dim3(1),    dim3(BTHR), 0, stream, xw, yw);
    hipLaunchKernelGGL(build_kernel, dim3(MBLK), dim3(BTHR), 0, stream, x, y);
    for (int it = 0; it < MAXIT; ++it) {
        hipLaunchKernelGGL(main_kernel,    dim3(MBLK), dim3(BTHR), 0, stream, it);
        hipLaunchKernelGGL(combine_kernel, dim3(16),   dim3(BTHR), 0, stream, it);
    }
    hipLaunchKernelGGL(cost_kernel, dim3(1024), dim3(BTHR), 0, stream);
    hipLaunchKernelGGL(out_kernel,  dim3(1),    dim3(64),   0, stream, out);
}